// Round 2
// baseline (1165.434 us; speedup 1.0000x reference)
//
#include <hip/hip_runtime.h>
#include <hip/hip_bf16.h>
#include <hip/hip_fp16.h>

// CrossAttention block, MI355X/gfx950.
// Pipeline: cvt->bf16 | qp/kp GEMM | vp GEMM (transposed fp16 out) |
//           fused 2-pass attention (writes attn [H,B,M,N] + ctx bf16) |
//           out-proj (+q resid, fp32) | LN | MLP1 (exact GELU) | MLP2 (+resid -> d_out)

typedef unsigned int uint;
typedef unsigned short ushort_t;
typedef short bf16x8 __attribute__((ext_vector_type(8)));
typedef _Float16 f16x4 __attribute__((ext_vector_type(4)));
typedef float f32x4 __attribute__((ext_vector_type(4)));
typedef unsigned short u16x4 __attribute__((ext_vector_type(4)));
typedef unsigned short u16x8 __attribute__((ext_vector_type(8)));

#define DEV static __device__ __forceinline__

DEV unsigned short f2bf(float f) {
    uint u = __float_as_uint(f);
    u += 0x7FFFu + ((u >> 16) & 1u);   // RNE
    return (unsigned short)(u >> 16);
}

DEV void gload_lds16(const void* g, void* l) {
    __builtin_amdgcn_global_load_lds(
        (const __attribute__((address_space(1))) void*)g,
        (__attribute__((address_space(3))) void*)l, 16, 0, 0);
}

// ---------------- fp32 -> bf16 conversion (8 elems/thread) ----------------
__global__ __launch_bounds__(256) void cvt_bf16_kernel(const float* __restrict__ in,
                                                       unsigned short* __restrict__ out,
                                                       int n8) {
    int i = blockIdx.x * 256 + threadIdx.x;
    if (i >= n8) return;
    const float4* p = (const float4*)in + (size_t)i * 2;
    float4 a = p[0], b = p[1];
    u16x8 o;
    o[0] = f2bf(a.x); o[1] = f2bf(a.y); o[2] = f2bf(a.z); o[3] = f2bf(a.w);
    o[4] = f2bf(b.x); o[5] = f2bf(b.y); o[6] = f2bf(b.z); o[7] = f2bf(b.w);
    *((u16x8*)out + (size_t)i) = o;
}

// ---------------- generic GEMM: C[M,N] = A[M,K] * W[N,K]^T + bias ----------------
// EPI: 0 = bf16 store; 1 = fp16 transposed store ([b][col][tok], V path);
//      2 = fp32 store + extra (q resid); 3 = bf16 store of exact GELU; 4 = fp32 + extra -> out
// tile 64x128, 4 waves (2x2), wave tile 32x64, BK=32, mfma 16x16x32 bf16.
template <int EPI>
__global__ __launch_bounds__(256) void gemm_bt(const unsigned short* __restrict__ A,
                                               const unsigned short* __restrict__ W,
                                               const float* __restrict__ bias,
                                               void* __restrict__ Cout,
                                               const float* __restrict__ extra,
                                               int M, int N, int K) {
    __shared__ unsigned short As[64 * 32];    // 4 KB
    __shared__ unsigned short Bs[128 * 32];   // 8 KB
    const int tid = threadIdx.x;
    const int wave = tid >> 6, lane = tid & 63;
    const int l15 = lane & 15, lh = lane >> 4;
    const int bm = blockIdx.x * 64, bn = blockIdx.y * 128;
    const int wm = (wave >> 1) * 32, wn = (wave & 1) * 64;

    f32x4 acc[2][4];
#pragma unroll
    for (int i = 0; i < 2; i++)
#pragma unroll
        for (int j = 0; j < 4; j++) acc[i][j] = f32x4{0.f, 0.f, 0.f, 0.f};

    const int srow = lane >> 2;        // 0..15 rows per wave-instr
    const int scol = (lane & 3) * 8;   // k element offset (16B blocks)

    for (int k0 = 0; k0 < K; k0 += 32) {
        // A tile: 64 rows x 32 k (4 KB): one gload per thread
        gload_lds16(A + (size_t)(bm + wave * 16 + srow) * K + k0 + scol,
                    (char*)As + wave * 1024);
        // B tile: 128 rows x 32 k (8 KB): two gloads per thread
#pragma unroll
        for (int i = 0; i < 2; i++)
            gload_lds16(W + (size_t)(bn + (i * 4 + wave) * 16 + srow) * K + k0 + scol,
                        (char*)Bs + (i * 4 + wave) * 1024);
        __syncthreads();

        bf16x8 af[2], bfr[4];
#pragma unroll
        for (int i = 0; i < 2; i++)
            af[i] = *(const bf16x8*)&As[(wm + i * 16 + l15) * 32 + lh * 8];
#pragma unroll
        for (int j = 0; j < 4; j++)
            bfr[j] = *(const bf16x8*)&Bs[(wn + j * 16 + l15) * 32 + lh * 8];
#pragma unroll
        for (int i = 0; i < 2; i++)
#pragma unroll
            for (int j = 0; j < 4; j++)
                acc[i][j] = __builtin_amdgcn_mfma_f32_16x16x32_bf16(af[i], bfr[j], acc[i][j], 0, 0, 0);
        __syncthreads();
    }

    // epilogue: lane holds col = l15, rows = lh*4 + r within each 16x16 fragment
#pragma unroll
    for (int i = 0; i < 2; i++) {
#pragma unroll
        for (int j = 0; j < 4; j++) {
            const int col = bn + wn + j * 16 + l15;
            const float bb = bias[col];
            const int row0 = bm + wm + i * 16 + lh * 4;
            if constexpr (EPI == 1) {
                // V path: store fp16 transposed: vpt[b][col][tok], 4 contiguous toks
                f16x4 o;
#pragma unroll
                for (int r = 0; r < 4; r++) o[r] = (_Float16)(acc[i][j][r] + bb);
                const int b_ = row0 >> 11, tok = row0 & 2047;
                *(f16x4*)((_Float16*)Cout + (size_t)b_ * (1024 * 2048) + (size_t)col * 2048 + tok) = o;
            } else {
#pragma unroll
                for (int r = 0; r < 4; r++) {
                    const int row = row0 + r;
                    const float v = acc[i][j][r] + bb;
                    const size_t idx = (size_t)row * N + col;
                    if constexpr (EPI == 0) {
                        ((unsigned short*)Cout)[idx] = f2bf(v);
                    } else if constexpr (EPI == 2) {
                        ((float*)Cout)[idx] = v + extra[idx];
                    } else if constexpr (EPI == 3) {
                        const float g = 0.5f * v * (1.0f + erff(v * 0.70710678118654752f));
                        ((unsigned short*)Cout)[idx] = f2bf(g);
                    } else {  // EPI == 4
                        ((float*)Cout)[idx] = v + extra[idx];
                    }
                }
            }
        }
    }
}

// ---------------- fused attention ----------------
// grid (8 mtiles, 16 heads, 4 batch), 256 thr = 4 waves, wave owns 32 q-rows.
// Computes S^T = mfma(A=K_tile, B=Q^T): lane -> col m = l15, rows n = lh*4+r.
// Pass 1: row sums of exp(s/8).  Pass 2: recompute, write normalized attn fp32,
// PV via mfma_f32_16x16x16f16 (P fragment layout == A operand layout, k-run=4).
__global__ __launch_bounds__(256) void attn_kernel(const unsigned short* __restrict__ qp,
                                                   const unsigned short* __restrict__ kp,
                                                   const _Float16* __restrict__ vpt,
                                                   float* __restrict__ attn_out,
                                                   unsigned short* __restrict__ ctx) {
    const int tid = threadIdx.x;
    const int wave = tid >> 6, lane = tid & 63;
    const int l15 = lane & 15, lh = lane >> 4;
    const int mt = blockIdx.x, h = blockIdx.y, b = blockIdx.z;
    const int m0 = mt * 128 + wave * 32;

    const unsigned short* qbase = qp + (size_t)b * 1024 * 1024 + h * 64;
    const unsigned short* kbase = kp + (size_t)b * 2048 * 1024 + h * 64;
    const _Float16* vbase = vpt + (size_t)b * 1024 * 2048 + (size_t)h * 64 * 2048;
    float* abase = attn_out + (size_t)(h * 4 + b) * 1024 * 2048;

    // Q fragments (B-operand): lane col m = l15, k-run = lh*8 (+kb*32)
    bf16x8 bq[2][2];
#pragma unroll
    for (int mf = 0; mf < 2; mf++)
#pragma unroll
        for (int kb = 0; kb < 2; kb++)
            bq[mf][kb] = *(const bf16x8*)(qbase + (size_t)(m0 + mf * 16 + l15) * 1024 + kb * 32 + lh * 8);

    // ---- pass 1: denominators ----
    float ssum[2] = {0.f, 0.f};
#pragma unroll 2
    for (int n0 = 0; n0 < 2048; n0 += 16) {
        const bf16x8 ka0 = *(const bf16x8*)(kbase + (size_t)(n0 + l15) * 1024 + lh * 8);
        const bf16x8 ka1 = *(const bf16x8*)(kbase + (size_t)(n0 + l15) * 1024 + 32 + lh * 8);
#pragma unroll
        for (int mf = 0; mf < 2; mf++) {
            f32x4 st = f32x4{0.f, 0.f, 0.f, 0.f};
            st = __builtin_amdgcn_mfma_f32_16x16x32_bf16(ka0, bq[mf][0], st, 0, 0, 0);
            st = __builtin_amdgcn_mfma_f32_16x16x32_bf16(ka1, bq[mf][1], st, 0, 0, 0);
#pragma unroll
            for (int r = 0; r < 4; r++) ssum[mf] += __expf(st[r] * 0.125f);
        }
    }
#pragma unroll
    for (int mf = 0; mf < 2; mf++) {
        ssum[mf] += __shfl_xor(ssum[mf], 16);
        ssum[mf] += __shfl_xor(ssum[mf], 32);
    }
    const float inv[2] = {1.0f / ssum[0], 1.0f / ssum[1]};

    // ---- pass 2: emit attn + accumulate PV ----
    f32x4 cacc[2][4];
#pragma unroll
    for (int mf = 0; mf < 2; mf++)
#pragma unroll
        for (int db = 0; db < 4; db++) cacc[mf][db] = f32x4{0.f, 0.f, 0.f, 0.f};

#pragma unroll 2
    for (int n0 = 0; n0 < 2048; n0 += 16) {
        const bf16x8 ka0 = *(const bf16x8*)(kbase + (size_t)(n0 + l15) * 1024 + lh * 8);
        const bf16x8 ka1 = *(const bf16x8*)(kbase + (size_t)(n0 + l15) * 1024 + 32 + lh * 8);
        f16x4 vb[4];
#pragma unroll
        for (int db = 0; db < 4; db++)
            vb[db] = *(const f16x4*)(vbase + (size_t)(db * 16 + l15) * 2048 + n0 + lh * 4);
#pragma unroll
        for (int mf = 0; mf < 2; mf++) {
            f32x4 st = f32x4{0.f, 0.f, 0.f, 0.f};
            st = __builtin_amdgcn_mfma_f32_16x16x32_bf16(ka0, bq[mf][0], st, 0, 0, 0);
            st = __builtin_amdgcn_mfma_f32_16x16x32_bf16(ka1, bq[mf][1], st, 0, 0, 0);
            f32x4 p;
            f16x4 pa;
#pragma unroll
            for (int r = 0; r < 4; r++) {
                const float e = __expf(st[r] * 0.125f) * inv[mf];
                p[r] = e;
                pa[r] = (_Float16)e;
            }
            // attn store: row m = m0+mf*16+l15, cols n0+lh*4 .. +3 (16B)
            *(f32x4*)(abase + (size_t)(m0 + mf * 16 + l15) * 2048 + n0 + lh * 4) = p;
#pragma unroll
            for (int db = 0; db < 4; db++)
                cacc[mf][db] = __builtin_amdgcn_mfma_f32_16x16x16f16(pa, vb[db], cacc[mf][db], 0, 0, 0);
        }
    }

    // ctx write: lane col d = db*16+l15, rows m = lh*4+r
#pragma unroll
    for (int mf = 0; mf < 2; mf++)
#pragma unroll
        for (int db = 0; db < 4; db++)
#pragma unroll
            for (int r = 0; r < 4; r++) {
                const int m = m0 + mf * 16 + lh * 4 + r;
                ctx[(size_t)(b * 1024 + m) * 1024 + h * 64 + db * 16 + l15] = f2bf(cacc[mf][db][r]);
            }
}

// ---------------- LayerNorm (row of 1024) -> bf16 ----------------
__global__ __launch_bounds__(256) void ln_kernel(const float* __restrict__ x,
                                                 const float* __restrict__ g,
                                                 const float* __restrict__ beta,
                                                 unsigned short* __restrict__ out) {
    const int row = blockIdx.x, tid = threadIdx.x;
    const float4 v = *((const float4*)(x + (size_t)row * 1024) + tid);
    float s = v.x + v.y + v.z + v.w;
    float s2 = v.x * v.x + v.y * v.y + v.z * v.z + v.w * v.w;
#pragma unroll
    for (int off = 32; off >= 1; off >>= 1) {
        s += __shfl_xor(s, off);
        s2 += __shfl_xor(s2, off);
    }
    __shared__ float sh[8];
    const int wave = tid >> 6, lane = tid & 63;
    if (lane == 0) { sh[wave] = s; sh[4 + wave] = s2; }
    __syncthreads();
    s = sh[0] + sh[1] + sh[2] + sh[3];
    s2 = sh[4] + sh[5] + sh[6] + sh[7];
    const float mean = s * (1.0f / 1024.0f);
    const float var = s2 * (1.0f / 1024.0f) - mean * mean;
    const float rstd = rsqrtf(var + 1e-5f);
    const float4 gv = *((const float4*)g + tid);
    const float4 bv = *((const float4*)beta + tid);
    u16x4 o;
    o[0] = f2bf((v.x - mean) * rstd * gv.x + bv.x);
    o[1] = f2bf((v.y - mean) * rstd * gv.y + bv.y);
    o[2] = f2bf((v.z - mean) * rstd * gv.z + bv.z);
    o[3] = f2bf((v.w - mean) * rstd * gv.w + bv.w);
    *((u16x4*)(out + (size_t)row * 1024) + tid) = o;
}

extern "C" void kernel_launch(void* const* d_in, const int* in_sizes, int n_in,
                              void* d_out, int out_size, void* d_ws, size_t ws_size,
                              hipStream_t stream) {
    const float* x   = (const float*)d_in[0];
    const float* q   = (const float*)d_in[1];
    const float* wq  = (const float*)d_in[2];
    const float* bq  = (const float*)d_in[3];
    const float* wk  = (const float*)d_in[4];
    const float* bk  = (const float*)d_in[5];
    const float* wv  = (const float*)d_in[6];
    const float* bv  = (const float*)d_in[7];
    const float* wo  = (const float*)d_in[8];
    const float* bo  = (const float*)d_in[9];
    const float* g2  = (const float*)d_in[10];
    const float* be2 = (const float*)d_in[11];
    const float* w1  = (const float*)d_in[12];
    const float* b1  = (const float*)d_in[13];
    const float* w2  = (const float*)d_in[14];
    const float* b2  = (const float*)d_in[15];

    float* out = (float*)d_out;
    float* attn = out + (size_t)4 * 1024 * 1024;  // [H,B,M,N] after out [B,M,D]

    char* ws = (char*)d_ws;
    const size_t MB = 1024 * 1024;
    unsigned short* q_bf  = (unsigned short*)(ws + 0);        // 8 MB  (dead after qp gemm)
    unsigned short* x_bf  = (unsigned short*)(ws + 8 * MB);   // 16 MB (dead after vp gemm)
    unsigned short* wq_bf = (unsigned short*)(ws + 24 * MB);  // 2 MB
    unsigned short* wk_bf = (unsigned short*)(ws + 26 * MB);
    unsigned short* wv_bf = (unsigned short*)(ws + 28 * MB);
    unsigned short* wo_bf = (unsigned short*)(ws + 30 * MB);
    unsigned short* w1_bf = (unsigned short*)(ws + 32 * MB);  // 8 MB
    unsigned short* w2_bf = (unsigned short*)(ws + 40 * MB);  // 8 MB
    unsigned short* qp_bf = (unsigned short*)(ws + 48 * MB);  // 8 MB
    unsigned short* kp_bf = (unsigned short*)(ws + 56 * MB);  // 16 MB
    _Float16*       vpt   = (_Float16*)(ws + 72 * MB);        // 16 MB
    unsigned short* ctx_bf = (unsigned short*)(ws + 88 * MB); // 8 MB
    float*          resid = (float*)(ws + 96 * MB);           // 16 MB
    unsigned short* hln_bf = (unsigned short*)(ws + 112 * MB);// 8 MB
    unsigned short* h1_bf = (unsigned short*)(ws + 0);        // 32 MB, overlays q_bf/x_bf (dead by then)

    auto cvt = [&](const float* in, unsigned short* o, int n) {
        const int n8 = n / 8;
        cvt_bf16_kernel<<<dim3((n8 + 255) / 256), dim3(256), 0, stream>>>(in, o, n8);
    };
    cvt(q, q_bf, 4 * 1024 * 1024);
    cvt(x, x_bf, 8 * 1024 * 1024);
    cvt(wq, wq_bf, 1024 * 1024);
    cvt(wk, wk_bf, 1024 * 1024);
    cvt(wv, wv_bf, 1024 * 1024);
    cvt(wo, wo_bf, 1024 * 1024);
    cvt(w1, w1_bf, 4 * 1024 * 1024);
    cvt(w2, w2_bf, 4 * 1024 * 1024);

    const dim3 blk(256);
    // projections
    gemm_bt<0><<<dim3(64, 8), blk, 0, stream>>>(q_bf, wq_bf, bq, qp_bf, nullptr, 4096, 1024, 1024);
    gemm_bt<0><<<dim3(128, 8), blk, 0, stream>>>(x_bf, wk_bf, bk, kp_bf, nullptr, 8192, 1024, 1024);
    gemm_bt<1><<<dim3(128, 8), blk, 0, stream>>>(x_bf, wv_bf, bv, vpt, nullptr, 8192, 1024, 1024);
    // attention (attn out + ctx)
    attn_kernel<<<dim3(8, 16, 4), blk, 0, stream>>>(qp_bf, kp_bf, vpt, attn, ctx_bf);
    // out proj + residual(q) -> resid fp32
    gemm_bt<2><<<dim3(64, 8), blk, 0, stream>>>(ctx_bf, wo_bf, bo, resid, q, 4096, 1024, 1024);
    // LN -> bf16
    ln_kernel<<<dim3(4096), blk, 0, stream>>>(resid, g2, be2, hln_bf);
    // MLP
    gemm_bt<3><<<dim3(64, 32), blk, 0, stream>>>(hln_bf, w1_bf, b1, h1_bf, nullptr, 4096, 4096, 1024);
    gemm_bt<4><<<dim3(64, 8), blk, 0, stream>>>(h1_bf, w2_bf, b2, out, resid, 4096, 1024, 4096);
}